// Round 6
// baseline (582.796 us; speedup 1.0000x reference)
//
#include <hip/hip_runtime.h>
#include <hip/hip_bf16.h>
#include <stdint.h>

typedef __attribute__((ext_vector_type(8))) short bf16x8;
typedef __attribute__((ext_vector_type(4))) short bf16x4;
typedef __attribute__((ext_vector_type(8))) unsigned short u16x8;
typedef __attribute__((ext_vector_type(4))) float f32x4;

#define B_SZ 2048
#define L_SZ 200
#define NROWS (B_SZ * L_SZ)   // 409600 (valid rows; blob has 208 rows/batch)

__device__ __forceinline__ short f2bf(float f) {
    __bf16 h = (__bf16)f;                    // hardware v_cvt (RNE)
    return __builtin_bit_cast(short, h);
}
__device__ __forceinline__ float bf2f(short s) {
    union { uint32_t u; float f; } v; v.u = ((uint32_t)(uint16_t)s) << 16;
    return v.f;
}
__device__ __forceinline__ float sigm(float x) {
    return 1.0f / (1.0f + __expf(-x));
}
// channel permutation: blob slot kap <-> actual channel c
// c = kt*32 + 16*mt + 4*g + j ; kap = kt*32 + 8*g + 4*mt + j
__device__ __forceinline__ int chan_to_slot(int c) {
    return (c & 96) | (((c >> 2) & 3) << 3) | (((c >> 4) & 1) << 2) | (c & 3);
}

// ---------------- K0: weight prep + stat zeroing ----------------
// Aprime = W1a + W1c (f32 128x128, natural)
// Bf32/Cf32: B'=W1b-W1c, C'=W1d as f32 frag blobs (same layout as before):
//   e: jj=e&7, l=(e>>3)&63, kt=(e>>9)&3, ct=e>>11 -> W[kt*32+(l>>4)*8+jj][ct*16+(l&15)]
// W2fT: A-frag blob of W2^T with PERMUTED rows: f: jj,l,kt,mt2 ->
//   W2[c(kap)][mt2*16+(l&15)], kap = kt*32+(l>>4)*8+jj
// alpha1p[kap] = alpha1[c]
__global__ void k0_prep(const float* __restrict__ W1, const float* __restrict__ W2,
                        const float* __restrict__ alpha1,
                        float* __restrict__ Aprime, float* __restrict__ Bf32,
                        float* __restrict__ Cf32, ushort* __restrict__ W2fT,
                        float* __restrict__ alpha1p, float* __restrict__ stats)
{
    const int total = 49152 + 4096 + 128 + 512;
    for (int i = blockIdx.x * blockDim.x + threadIdx.x; i < total; i += gridDim.x * blockDim.x) {
        if (i < 16384) {
            int r = i >> 7, c = i & 127;
            Aprime[i] = W1[r * 128 + c] + W1[(256 + r) * 128 + c];
        } else if (i < 32768) {
            int e = i - 16384;
            int jj = e & 7, l = (e >> 3) & 63, kt = (e >> 9) & 3, ct = e >> 11;
            int k = kt * 32 + ((l >> 4) << 3) + jj;
            int col = (ct << 4) + (l & 15);
            Bf32[e] = W1[(128 + k) * 128 + col] - W1[(256 + k) * 128 + col];
        } else if (i < 49152) {
            int e = i - 32768;
            int jj = e & 7, l = (e >> 3) & 63, kt = (e >> 9) & 3, ct = e >> 11;
            int k = kt * 32 + ((l >> 4) << 3) + jj;
            int col = (ct << 4) + (l & 15);
            Cf32[e] = W1[(384 + k) * 128 + col];
        } else if (i < 49152 + 4096) {
            int f = i - 49152;
            int jj = f & 7, l = (f >> 3) & 63, kt = (f >> 9) & 3, mt2 = f >> 11;
            int g = l >> 4;
            int c = kt * 32 + ((jj >> 2) << 4) + (g << 2) + (jj & 3);  // c(kap)
            int col = (mt2 << 4) + (l & 15);
            W2fT[f] = (ushort)f2bf(W2[c * 32 + col]);
        } else if (i < 49152 + 4096 + 128) {
            int c = i - (49152 + 4096);
            alpha1p[chan_to_slot(c)] = alpha1[c];
        } else {
            stats[i - (49152 + 4096 + 128)] = 0.0f;  // 512 f32: stats1(256) + stats2(64) + pad
        }
    }
}

// ---------------- K1: qA[b][c] = q[b]@A' + b1 ----------------
__global__ void k1_qA(const float* __restrict__ q, const float* __restrict__ Aprime,
                      const float* __restrict__ b1, float* __restrict__ qA)
{
    __shared__ float qs[128];
    int b = blockIdx.x, c = threadIdx.x;
    qs[c] = q[b * 128 + c];
    __syncthreads();
    float acc = b1[c];
    #pragma unroll 8
    for (int r = 0; r < 128; ++r) acc += qs[r] * Aprime[r * 128 + c];
    qA[b * 128 + c] = acc;
}

// ---------------- K2: z1^T = Wb^T @ k^T, blob stores, stats1 ----------------
// block = (batch, half); 4 waves = 4 column groups (32 ch each).
// Operand-swapped MFMA: lane holds key-row r15 x 8 channels -> one coalesced
// b128 store per tile per lane directly in K4's frag order. No LDS.
__global__ void __launch_bounds__(256, 3) k2_main(
    const float* __restrict__ query, const float* __restrict__ keys,
    const float* __restrict__ qA, const float* __restrict__ Bf32,
    const float* __restrict__ Cf32, ushort* __restrict__ z1b,
    float* __restrict__ stats1)
{
    const int tid = threadIdx.x, lane = tid & 63, cg = tid >> 6;
    const int b = blockIdx.x >> 1, half = blockIdx.x & 1;
    const int r15 = lane & 15, g = lane >> 4;
    const int t0 = half * 7, tE = half ? 13 : 7;

    const float* kbase = keys + (size_t)b * L_SZ * 128;

    // prefetch first keys tile (issue before weight build)
    f32x4 kv[4][2];
    {
        const float* kp = kbase + (size_t)min(t0 * 16 + r15, L_SZ - 1) * 128 + g * 8;
        #pragma unroll
        for (int kt = 0; kt < 4; ++kt) {
            kv[kt][0] = *(const f32x4*)(kp + kt * 32);
            kv[kt][1] = *(const f32x4*)(kp + kt * 32 + 4);
        }
    }

    // q fragments
    f32x4 qv[4][2];
    #pragma unroll
    for (int kt = 0; kt < 4; ++kt) {
        const float* qp = query + (size_t)b * 128 + kt * 32 + g * 8;
        qv[kt][0] = *(const f32x4*)(qp);
        qv[kt][1] = *(const f32x4*)(qp + 4);
    }

    // Wb = B' + diag(q)*C', 8 frags (used as A-operand = Wb^T)
    bf16x8 wb[2][4];
    #pragma unroll
    for (int mt = 0; mt < 2; ++mt)
        #pragma unroll
        for (int kt = 0; kt < 4; ++kt) {
            const int ct = cg * 2 + mt;
            const int fi = ((ct * 4 + kt) * 64 + lane) * 8;
            f32x4 b0 = *(const f32x4*)(Bf32 + fi);
            f32x4 b1v = *(const f32x4*)(Bf32 + fi + 4);
            f32x4 c0 = *(const f32x4*)(Cf32 + fi);
            f32x4 c1 = *(const f32x4*)(Cf32 + fi + 4);
            bf16x8 w;
            #pragma unroll
            for (int j = 0; j < 4; ++j) {
                w[j]     = f2bf(b0[j]  + qv[kt][0][j] * c0[j]);
                w[4 + j] = f2bf(b1v[j] + qv[kt][1][j] * c1[j]);
            }
            wb[mt][kt] = w;
        }

    // qA for this lane's channels: c = cg*32 + mt*16 + g*4 + j
    f32x4 qa2[2];
    #pragma unroll
    for (int mt = 0; mt < 2; ++mt)
        qa2[mt] = *(const f32x4*)(qA + (size_t)b * 128 + cg * 32 + mt * 16 + g * 4);

    float ssum[2][4] = {{0}}, ssq[2][4] = {{0}};
    ushort* zb = z1b + (size_t)b * 13 * 2048;   // 2048 ushorts per tile

    for (int t = t0; t < tE; ++t) {
        // keys^T B-frags (element jj: keys[row=l&15][d=g*8+jj+32kt])
        bf16x8 afr[4];
        #pragma unroll
        for (int kt = 0; kt < 4; ++kt) {
            bf16x8 a;
            #pragma unroll
            for (int j = 0; j < 4; ++j) { a[j] = f2bf(kv[kt][0][j]); a[4 + j] = f2bf(kv[kt][1][j]); }
            afr[kt] = a;
        }
        if (t + 1 < tE) {
            const float* kp = kbase + (size_t)min((t + 1) * 16 + r15, L_SZ - 1) * 128 + g * 8;
            #pragma unroll
            for (int kt = 0; kt < 4; ++kt) {
                kv[kt][0] = *(const f32x4*)(kp + kt * 32);
                kv[kt][1] = *(const f32x4*)(kp + kt * 32 + 4);
            }
        }

        f32x4 acc[2];
        #pragma unroll
        for (int mt = 0; mt < 2; ++mt) {
            acc[mt] = (f32x4){0, 0, 0, 0};
            #pragma unroll
            for (int kt = 0; kt < 4; ++kt)
                acc[mt] = __builtin_amdgcn_mfma_f32_16x16x32_bf16(wb[mt][kt], afr[kt], acc[mt], 0, 0, 0);
        }

        // lane = key-row r15; acc[mt][j] = z1[row][c=cg*32+mt*16+g*4+j]
        const bool valid = (t * 16 + r15) < L_SZ;
        bf16x8 out;
        #pragma unroll
        for (int mt = 0; mt < 2; ++mt)
            #pragma unroll
            for (int j = 0; j < 4; ++j) {
                float v = acc[mt][j] + qa2[mt][j];
                if (valid) { ssum[mt][j] += v; ssq[mt][j] += v * v; }
                out[mt * 4 + j] = f2bf(v);   // slot jj = mt*4+j
            }
        *(bf16x8*)(zb + (size_t)t * 2048 + cg * 512 + lane * 8) = out;
    }

    // sum over rows = over r15 within each 16-lane group
    #pragma unroll
    for (int mt = 0; mt < 2; ++mt)
        #pragma unroll
        for (int j = 0; j < 4; ++j) {
            float s = ssum[mt][j], q2 = ssq[mt][j];
            s += __shfl_xor(s, 1); s += __shfl_xor(s, 2); s += __shfl_xor(s, 4); s += __shfl_xor(s, 8);
            q2 += __shfl_xor(q2, 1); q2 += __shfl_xor(q2, 2); q2 += __shfl_xor(q2, 4); q2 += __shfl_xor(q2, 8);
            if (r15 == 0) {
                int c = cg * 32 + mt * 16 + g * 4 + j;
                atomicAdd(&stats1[c], s);
                atomicAdd(&stats1[128 + c], q2);
            }
        }
}

// ---------------- k_fin1p: finalize stats1 -> PERMUTED rstd/bias ----------------
__global__ void k_fin1p(const float* __restrict__ raw, float* __restrict__ fin1p)
{
    int c = threadIdx.x;   // 128
    float n = (float)NROWS;
    float m = raw[c] / n;
    float v = raw[128 + c] / n - m * m;
    float r = rsqrtf(v + 1e-8f);
    int kap = chan_to_slot(c);
    fin1p[kap] = r;
    fin1p[128 + kap] = -m * r;
}

// ---------------- k_fin: natural-order finalize (stats2) ----------------
__global__ void k_fin(const float* __restrict__ raw, float* __restrict__ fin, int nch)
{
    int c = threadIdx.x;
    if (c >= nch) return;
    float n = (float)NROWS;
    float m = raw[c] / n;
    float v = raw[nch + c] / n - m * m;
    float r = rsqrtf(v + 1e-8f);
    fin[c] = r;
    fin[nch + c] = -m * r;
}

// ---------------- K4: dice1(blob) -> z2^T = W2^T @ h^T -> z2 (bf16), stats2 ----
// block = (batch, half); wave w handles tiles {half*7+w, +4}. Blob loads are
// frag-ready coalesced b128; dice params linear in slot order; GEMM2 B-operand
// is the dice output registers directly.
__global__ void __launch_bounds__(256, 3) k4_z2(
    const ushort* __restrict__ z1b, const ushort* __restrict__ W2fT,
    const float* __restrict__ fin1p, const float* __restrict__ alpha1p,
    const float* __restrict__ b2, ushort* __restrict__ z2,
    float* __restrict__ stats2)
{
    __shared__ float par[384];            // [0..127] rstd, [128..255] bias0, [256..383] alpha (slot order)
    __shared__ float red[4][64];
    __shared__ __align__(16) ushort stg[4][640];   // 16 rows x 40 (pad) per wave

    const int tid = threadIdx.x, lane = tid & 63, wid = tid >> 6;
    const int b = blockIdx.x >> 1, half = blockIdx.x & 1;
    const int r15 = lane & 15, g = lane >> 4;

    for (int i = tid; i < 384; i += 256) par[i] = (i < 256) ? fin1p[i] : alpha1p[i - 256];
    __syncthreads();

    // W2^T A-frags (rows permuted to slot order at prep)
    bf16x8 bfr[2][4];
    #pragma unroll
    for (int mt2 = 0; mt2 < 2; ++mt2)
        #pragma unroll
        for (int kt = 0; kt < 4; ++kt)
            bfr[mt2][kt] = *(const bf16x8*)(W2fT + ((size_t)(mt2 * 4 + kt) * 64 + lane) * 8);

    f32x4 b2v[2];
    #pragma unroll
    for (int mt2 = 0; mt2 < 2; ++mt2)
        b2v[mt2] = *(const f32x4*)(b2 + mt2 * 16 + g * 4);

    float ssum[2][4] = {{0}}, ssq[2][4] = {{0}};
    const ushort* zb = z1b + (size_t)b * 13 * 2048;
    ushort* stgw = stg[wid];
    const int tE = half ? 13 : 7;

    for (int t = half * 7 + wid; t < tE; t += 4) {
        bf16x8 zv[4];
        #pragma unroll
        for (int kt = 0; kt < 4; ++kt)
            zv[kt] = *(const bf16x8*)(zb + (size_t)t * 2048 + kt * 512 + lane * 8);

        // dice1 -> h frags (B-operand ready)
        bf16x8 hv[4];
        #pragma unroll
        for (int kt = 0; kt < 4; ++kt) {
            const int base = kt * 32 + g * 8;
            f32x4 r0 = *(const f32x4*)(par + base);
            f32x4 r1 = *(const f32x4*)(par + base + 4);
            f32x4 o0 = *(const f32x4*)(par + 128 + base);
            f32x4 o1 = *(const f32x4*)(par + 128 + base + 4);
            f32x4 a0 = *(const f32x4*)(par + 256 + base);
            f32x4 a1 = *(const f32x4*)(par + 256 + base + 4);
            bf16x8 h;
            #pragma unroll
            for (int j = 0; j < 4; ++j) {
                float zl = bf2f(zv[kt][j]);
                float pg = sigm(zl * r0[j] + o0[j]);
                h[j] = f2bf(zl * (pg + (1.0f - pg) * a0[j]));
                float zh = bf2f(zv[kt][4 + j]);
                float ph = sigm(zh * r1[j] + o1[j]);
                h[4 + j] = f2bf(zh * (ph + (1.0f - ph) * a1[j]));
            }
            hv[kt] = h;
        }

        f32x4 acc[2];
        #pragma unroll
        for (int mt2 = 0; mt2 < 2; ++mt2) {
            acc[mt2] = (f32x4){0, 0, 0, 0};
            #pragma unroll
            for (int kt = 0; kt < 4; ++kt)
                acc[mt2] = __builtin_amdgcn_mfma_f32_16x16x32_bf16(bfr[mt2][kt], hv[kt], acc[mt2], 0, 0, 0);
        }

        // lane = key-row r15; acc[mt2][j] = z2[row][ch2 = mt2*16+g*4+j]
        const bool valid = (t * 16 + r15) < L_SZ;
        #pragma unroll
        for (int mt2 = 0; mt2 < 2; ++mt2) {
            bf16x4 o;
            #pragma unroll
            for (int j = 0; j < 4; ++j) {
                float v = acc[mt2][j] + b2v[mt2][j];
                if (valid) { ssum[mt2][j] += v; ssq[mt2][j] += v * v; }
                o[j] = f2bf(v);
            }
            *(bf16x4*)(stgw + r15 * 40 + mt2 * 16 + g * 4) = o;
        }
        // coalesced z2 store: 16 rows x 64B
        u16x8 vv = *(const u16x8*)(stgw + (lane >> 2) * 40 + (lane & 3) * 8);
        *(u16x8*)(z2 + ((size_t)b * 208 + t * 16 + (lane >> 2)) * 32 + (lane & 3) * 8) = vv;
    }

    #pragma unroll
    for (int mt2 = 0; mt2 < 2; ++mt2)
        #pragma unroll
        for (int j = 0; j < 4; ++j) {
            float s = ssum[mt2][j], q2 = ssq[mt2][j];
            s += __shfl_xor(s, 1); s += __shfl_xor(s, 2); s += __shfl_xor(s, 4); s += __shfl_xor(s, 8);
            q2 += __shfl_xor(q2, 1); q2 += __shfl_xor(q2, 2); q2 += __shfl_xor(q2, 4); q2 += __shfl_xor(q2, 8);
            if (r15 == 0) {
                int c2 = mt2 * 16 + g * 4 + j;
                red[wid][c2] = s;
                red[wid][32 + c2] = q2;
            }
        }
    __syncthreads();
    if (tid < 64) {
        float v = red[0][tid] + red[1][tid] + red[2][tid] + red[3][tid];
        atomicAdd(&stats2[tid], v);
    }
}

// ---------------- K6: score = dice(z2)@Wd + bd, mask, pool over valid L ----------------
__global__ void __launch_bounds__(256) k6_score_pool(
    const ushort* __restrict__ z2, const float* __restrict__ keys,
    const int* __restrict__ keys_len, const float* __restrict__ fin2,
    const float* __restrict__ alpha2, const float* __restrict__ Wd,
    const float* __restrict__ bd, float* __restrict__ out)
{
    __shared__ float pp[129];      // [0..31] rstd2, [32..63] bias2, [64..95] alpha2, [96..127] Wd, [128] bd
    __shared__ float sc[200];
    __shared__ float part[2][128];
    int b = blockIdx.x, t = threadIdx.x;
    if (t < 64) pp[t] = fin2[t];
    else if (t < 96) pp[t] = alpha2[t - 64];
    else if (t < 128) pp[t] = Wd[t - 96];
    else if (t == 128) pp[128] = bd[0];
    __syncthreads();

    int klen = keys_len[b];
    if (t < 200) {
        float s = 0.0f;
        if (t < klen) {
            const ushort* zp = z2 + ((size_t)b * 208 + t) * 32;
            u16x8 zr[4];
            #pragma unroll
            for (int i = 0; i < 4; ++i) zr[i] = ((const u16x8*)zp)[i];
            s = pp[128];
            #pragma unroll
            for (int c = 0; c < 32; ++c) {
                float z = bf2f((short)zr[c >> 3][c & 7]);
                float zh = z * pp[c] + pp[32 + c];
                float pg = sigm(zh);
                float h = z * (pg + (1.0f - pg) * pp[64 + c]);
                s += h * pp[96 + c];
            }
        }
        sc[t] = s;
    }
    __syncthreads();

    int c = t & 127, prt = t >> 7;
    int lim = min(100, klen - prt * 100);     // may be <=0
    const float* kp = keys + ((size_t)b * 200 + prt * 100) * 128 + c;
    float acc = 0.0f;
    #pragma unroll 4
    for (int l = 0; l < lim; ++l) acc += sc[prt * 100 + l] * kp[(size_t)l * 128];
    part[prt][c] = acc;
    __syncthreads();
    if (t < 128) out[(size_t)b * 128 + t] = part[0][t] + part[1][t];
}

// ---------------- host launch ----------------
extern "C" void kernel_launch(void* const* d_in, const int* in_sizes, int n_in,
                              void* d_out, int out_size, void* d_ws, size_t ws_size,
                              hipStream_t stream) {
    const float* query    = (const float*)d_in[0];
    const float* keys     = (const float*)d_in[1];
    const int*   keys_len = (const int*)d_in[2];
    const float* W1       = (const float*)d_in[3];
    const float* b1       = (const float*)d_in[4];
    const float* alpha1   = (const float*)d_in[5];
    const float* W2       = (const float*)d_in[6];
    const float* b2       = (const float*)d_in[7];
    const float* alpha2   = (const float*)d_in[8];
    const float* Wd       = (const float*)d_in[9];
    const float* bd       = (const float*)d_in[10];
    float* out = (float*)d_out;

    char* ws = (char*)d_ws;
    ushort* z1b    = (ushort*)(ws);                          // 109051904 B (2048*13 tiles * 4KB)
    ushort* z2     = (ushort*)(ws + 109051904);              // 27262976 B (2048*208*32 bf16)
    float*  qA     = (float*)(ws + 136314880);               // 1048576 B
    float*  Aprime = (float*)(ws + 137363456);               // 65536 B
    float*  Bf32   = (float*)(ws + 137428992);               // 65536 B
    float*  Cf32   = (float*)(ws + 137494528);               // 65536 B
    ushort* W2fT   = (ushort*)(ws + 137560064);              // 8192 B
    float*  alpha1p= (float*)(ws + 137568256);               // 512 B
    float*  stats  = (float*)(ws + 137568768);               // 2048 B (512 f32)
    float*  fin1p  = (float*)(ws + 137570816);               // 1024 B
    float*  fin2   = (float*)(ws + 137571840);               // 256 B

    k0_prep<<<128, 256, 0, stream>>>(W1, W2, alpha1, Aprime, Bf32, Cf32, W2fT, alpha1p, stats);
    k1_qA<<<B_SZ, 128, 0, stream>>>(query, Aprime, b1, qA);
    k2_main<<<2 * B_SZ, 256, 0, stream>>>(query, keys, qA, Bf32, Cf32, z1b, stats);
    k_fin1p<<<1, 128, 0, stream>>>(stats, fin1p);
    k4_z2<<<2 * B_SZ, 256, 0, stream>>>(z1b, W2fT, fin1p, alpha1p, b2, z2, stats + 256);
    k_fin<<<1, 32, 0, stream>>>(stats + 256, fin2, 32);
    k6_score_pool<<<B_SZ, 256, 0, stream>>>(z2, keys, keys_len, fin2, alpha2, Wd, bd, out);
}